// Round 1
// baseline (202.640 us; speedup 1.0000x reference)
//
#include <hip/hip_runtime.h>
#include <hip/hip_bf16.h>

#define DDIM 512
#define NROWS 6144

typedef __attribute__((ext_vector_type(8))) short short8;
typedef __attribute__((ext_vector_type(4))) float f32x4;

// ---------------------------------------------------------------------------
// Fold the 4 [512,512] blocks of W [2048,512] (sum over blocks), transpose to
// [n][k], cast to bf16.  LDS-tiled 64x64 transpose so both global read and
// write are coalesced.
// ---------------------------------------------------------------------------
__global__ __launch_bounds__(256) void fold_transpose_w(
    const float* __restrict__ W,          // [2048, 512] row-major
    __hip_bfloat16* __restrict__ Wt) {    // [512, 512]  (n, k) row-major
    __shared__ float lds[64][65];
    const int k0 = blockIdx.x * 64;
    const int n0 = blockIdx.y * 64;
    #pragma unroll
    for (int e = 0; e < 16; ++e) {
        int idx = e * 256 + threadIdx.x;
        int kk = idx >> 6, nn = idx & 63;
        float s = 0.f;
        #pragma unroll
        for (int i = 0; i < 4; ++i)
            s += W[(size_t)(i * 512 + k0 + kk) * 512 + (n0 + nn)];
        lds[kk][nn] = s;
    }
    __syncthreads();
    #pragma unroll
    for (int e = 0; e < 16; ++e) {
        int idx = e * 256 + threadIdx.x;
        int nn = idx >> 6, kk = idx & 63;
        Wt[(size_t)(n0 + nn) * 512 + (k0 + kk)] = __float2bfloat16(lds[kk][nn]);
    }
}

// ---------------------------------------------------------------------------
// f32 -> bf16 cast, vectorized: float4 in, 4x bf16 (8B) out.
// ---------------------------------------------------------------------------
__global__ __launch_bounds__(256) void cast_to_bf16(
    const float* __restrict__ in, __hip_bfloat16* __restrict__ out, int n4) {
    int i = blockIdx.x * blockDim.x + threadIdx.x;
    if (i >= n4) return;
    float4 v = ((const float4*)in)[i];
    __hip_bfloat16 h0 = __float2bfloat16(v.x);
    __hip_bfloat16 h1 = __float2bfloat16(v.y);
    __hip_bfloat16 h2 = __float2bfloat16(v.z);
    __hip_bfloat16 h3 = __float2bfloat16(v.w);
    ushort4 o;
    o.x = *(const unsigned short*)&h0;
    o.y = *(const unsigned short*)&h1;
    o.z = *(const unsigned short*)&h2;
    o.w = *(const unsigned short*)&h3;
    ((ushort4*)out)[i] = o;
}

// ---------------------------------------------------------------------------
// C[6144,512] = A[6144,512] @ W[512,512] + bias, bf16 MFMA, no LDS.
// W is pre-transposed: Wt[n][k].  B-operand fragment (B[k][n], n=l&15,
// k=(l>>4)*8+j) is then a contiguous 16B row-read of Wt -> L2-resident loads.
// Wave computes 16 rows x 128 cols (8 x 16x16 tiles).  Block = 4 waves =
// 64 rows x 128 cols.  blockIdx.z selects {atoms,cf} vs {amino,pf}.
// ---------------------------------------------------------------------------
__global__ __launch_bounds__(256) void gemm_bias(
    const __hip_bfloat16* __restrict__ Aall,   // [2][6144][512]
    const __hip_bfloat16* __restrict__ Wtall,  // [2][512][512]
    const float* __restrict__ bias0, const float* __restrict__ bias1,
    float* __restrict__ C) {                   // [2][6144][512]
    const int z = blockIdx.z;
    const unsigned short* A  = (const unsigned short*)Aall  + (size_t)z * NROWS * DDIM;
    const unsigned short* Wt = (const unsigned short*)Wtall + (size_t)z * DDIM * DDIM;
    const float* bias = z ? bias1 : bias0;
    float* Cz = C + (size_t)z * NROWS * DDIM;

    const int tid = threadIdx.x;
    const int w = tid >> 6;          // wave 0..3
    const int l = tid & 63;          // lane
    const int m0 = blockIdx.x * 64 + w * 16;
    const int n0 = blockIdx.y * 128;
    const int lrow = l & 15;
    const int lk   = (l >> 4) * 8;   // k-offset within 32-wide K-step

    f32x4 acc[8];
    #pragma unroll
    for (int j = 0; j < 8; ++j) acc[j] = (f32x4){0.f, 0.f, 0.f, 0.f};

    const unsigned short* ap = A + (size_t)(m0 + lrow) * DDIM + lk;
    const unsigned short* bp0 = Wt + (size_t)(n0 + lrow) * DDIM + lk;

    #pragma unroll 2
    for (int k0 = 0; k0 < DDIM; k0 += 32) {
        short8 a = *(const short8*)(ap + k0);
        #pragma unroll
        for (int j = 0; j < 8; ++j) {
            short8 b = *(const short8*)(bp0 + (size_t)j * 16 * DDIM + k0);
            acc[j] = __builtin_amdgcn_mfma_f32_16x16x32_bf16(a, b, acc[j], 0, 0, 0);
        }
    }

    const int r0 = (l >> 4) * 4;
    #pragma unroll
    for (int j = 0; j < 8; ++j) {
        const int col = n0 + j * 16 + lrow;
        const float bv = bias[col];
        #pragma unroll
        for (int r = 0; r < 4; ++r)
            Cz[(size_t)(m0 + r0 + r) * DDIM + col] = acc[j][r] + bv;
    }
}

extern "C" void kernel_launch(void* const* d_in, const int* in_sizes, int n_in,
                              void* d_out, int out_size, void* d_ws, size_t ws_size,
                              hipStream_t stream) {
    const float* atoms = (const float*)d_in[0];   // [6144,512]
    const float* amino = (const float*)d_in[1];   // [6144,512]
    const float* Wcc   = (const float*)d_in[15];  // [2048,512]
    const float* bcc   = (const float*)d_in[16];  // [512]
    const float* Wcp   = (const float*)d_in[17];  // [2048,512]
    const float* bcp   = (const float*)d_in[18];  // [512]
    float* out = (float*)d_out;

    // ws layout: A_bf16[2][6144][512] then Wt_bf16[2][512][512]
    __hip_bfloat16* Abf  = (__hip_bfloat16*)d_ws;
    __hip_bfloat16* A0   = Abf;
    __hip_bfloat16* A1   = Abf + (size_t)NROWS * DDIM;
    __hip_bfloat16* Wt   = Abf + (size_t)2 * NROWS * DDIM;
    __hip_bfloat16* Wt0  = Wt;
    __hip_bfloat16* Wt1  = Wt + (size_t)DDIM * DDIM;

    // 1) fold + transpose + cast weights
    dim3 fgrid(DDIM / 64, DDIM / 64, 1);
    fold_transpose_w<<<fgrid, 256, 0, stream>>>(Wcc, Wt0);
    fold_transpose_w<<<fgrid, 256, 0, stream>>>(Wcp, Wt1);

    // 2) cast activations
    const int n4 = NROWS * DDIM / 4;
    cast_to_bf16<<<(n4 + 255) / 256, 256, 0, stream>>>(atoms, A0, n4);
    cast_to_bf16<<<(n4 + 255) / 256, 256, 0, stream>>>(amino, A1, n4);

    // 3) GEMM + bias, both matrices in one launch (blockIdx.z)
    dim3 ggrid(NROWS / 64, DDIM / 128, 2);
    gemm_bias<<<ggrid, 256, 0, stream>>>(Abf, Wt, bcc, bcp, out);
}

// Round 2
// 172.142 us; speedup vs baseline: 1.1772x; 1.1772x over previous
//
#include <hip/hip_runtime.h>
#include <hip/hip_bf16.h>

#define DDIM 512
#define NROWS 6144

typedef __attribute__((ext_vector_type(8))) short short8;
typedef __attribute__((ext_vector_type(4))) float f32x4;

// ---------------------------------------------------------------------------
// Fold the 4 [512,512] k-blocks of W [2048,512] (sum), transpose to Wt[n][k],
// cast bf16.  32x32 LDS tiles, grid (16,16,2) = 512 blocks (both matrices in
// one dispatch via blockIdx.z).
// ---------------------------------------------------------------------------
__global__ __launch_bounds__(256) void prep_w(
    const float* __restrict__ Wcc, const float* __restrict__ Wcp,
    __hip_bfloat16* __restrict__ Wt) {
    const float* W = blockIdx.z ? Wcp : Wcc;
    unsigned short* o = (unsigned short*)Wt + (size_t)blockIdx.z * DDIM * DDIM;
    __shared__ float lds[32][33];
    const int k0 = blockIdx.x * 32, n0 = blockIdx.y * 32;
    #pragma unroll
    for (int e = 0; e < 4; ++e) {
        int idx = e * 256 + threadIdx.x;
        int kk = idx >> 5, nn = idx & 31;
        float s = 0.f;
        #pragma unroll
        for (int i = 0; i < 4; ++i)
            s += W[(size_t)(i * DDIM + k0 + kk) * DDIM + n0 + nn];
        lds[kk][nn] = s;
    }
    __syncthreads();
    #pragma unroll
    for (int e = 0; e < 4; ++e) {
        int idx = e * 256 + threadIdx.x;
        int nn = idx >> 5, kk = idx & 31;
        __hip_bfloat16 h = __float2bfloat16(lds[kk][nn]);
        o[(size_t)(n0 + nn) * DDIM + k0 + kk] = *(unsigned short*)&h;
    }
}

// ---------------------------------------------------------------------------
// C[6144,512] = A_f32[6144,512] @ W[512,512] + bias.  A converted f32->bf16
// in-register (no cast kernel).  Wt is [n][k] so B fragments are contiguous
// 16B row reads (L2-resident, 512 KB).  Register double-buffering: iteration
// it prefetches it+1's A (2x float4) and B (8x short8), so MFMAs never wait
// on same-iteration loads.  Wave = 16 rows x 128 cols (8 acc tiles);
// block = 4 waves = 64x128; grid (96,4,2) = 768 blocks = 3/CU.
// ---------------------------------------------------------------------------
__global__ __launch_bounds__(256, 3) void gemm_bias(
    const float* __restrict__ Aat, const float* __restrict__ Aam,
    const __hip_bfloat16* __restrict__ Wtall,
    const float* __restrict__ bias0, const float* __restrict__ bias1,
    float* __restrict__ C) {
    const int z = blockIdx.z;
    const float* A = z ? Aam : Aat;
    const unsigned short* Wt = (const unsigned short*)Wtall + (size_t)z * DDIM * DDIM;
    const float* bias = z ? bias1 : bias0;
    float* Cz = C + (size_t)z * NROWS * DDIM;

    const int tid = threadIdx.x;
    const int w = tid >> 6, l = tid & 63;
    const int m0 = blockIdx.x * 64 + w * 16;
    const int n0 = blockIdx.y * 128;
    const int lrow = l & 15;
    const int lk = (l >> 4) * 8;

    const float* ap = A + (size_t)(m0 + lrow) * DDIM + lk;
    const unsigned short* bp = Wt + (size_t)(n0 + lrow) * DDIM + lk;

    f32x4 acc[8];
    #pragma unroll
    for (int j = 0; j < 8; ++j) acc[j] = (f32x4){0.f, 0.f, 0.f, 0.f};

    // preload k-step 0
    float4 a0 = *(const float4*)(ap);
    float4 a1 = *(const float4*)(ap + 4);
    short8 b[8];
    #pragma unroll
    for (int j = 0; j < 8; ++j)
        b[j] = *(const short8*)(bp + (size_t)j * 16 * DDIM);

    #pragma unroll
    for (int it = 0; it < 16; ++it) {
        const int k0 = it * 32;
        float4 a0n, a1n;
        short8 bn[8];
        if (it < 15) {  // prefetch next k-step
            a0n = *(const float4*)(ap + k0 + 32);
            a1n = *(const float4*)(ap + k0 + 36);
            #pragma unroll
            for (int j = 0; j < 8; ++j)
                bn[j] = *(const short8*)(bp + (size_t)j * 16 * DDIM + k0 + 32);
        }
        // convert current A fragment f32 -> bf16
        short8 af;
        {
            float av[8] = {a0.x, a0.y, a0.z, a0.w, a1.x, a1.y, a1.z, a1.w};
            #pragma unroll
            for (int e = 0; e < 8; ++e) {
                __hip_bfloat16 h = __float2bfloat16(av[e]);
                af[e] = *(short*)&h;
            }
        }
        #pragma unroll
        for (int j = 0; j < 8; ++j)
            acc[j] = __builtin_amdgcn_mfma_f32_16x16x32_bf16(af, b[j], acc[j], 0, 0, 0);
        if (it < 15) {
            a0 = a0n; a1 = a1n;
            #pragma unroll
            for (int j = 0; j < 8; ++j) b[j] = bn[j];
        }
    }

    const int r0 = (l >> 4) * 4;
    #pragma unroll
    for (int j = 0; j < 8; ++j) {
        const int col = n0 + j * 16 + lrow;
        const float bv = bias[col];
        #pragma unroll
        for (int r = 0; r < 4; ++r)
            Cz[(size_t)(m0 + r0 + r) * DDIM + col] = acc[j][r] + bv;
    }
}

extern "C" void kernel_launch(void* const* d_in, const int* in_sizes, int n_in,
                              void* d_out, int out_size, void* d_ws, size_t ws_size,
                              hipStream_t stream) {
    const float* atoms = (const float*)d_in[0];   // [6144,512]
    const float* amino = (const float*)d_in[1];   // [6144,512]
    const float* Wcc   = (const float*)d_in[15];  // [2048,512]
    const float* bcc   = (const float*)d_in[16];  // [512]
    const float* Wcp   = (const float*)d_in[17];  // [2048,512]
    const float* bcp   = (const float*)d_in[18];  // [512]
    float* out = (float*)d_out;

    __hip_bfloat16* Wt = (__hip_bfloat16*)d_ws;   // [2][512][512] bf16 = 1 MB

    // 1) fold + transpose + cast weights (both matrices, one dispatch)
    dim3 fgrid(DDIM / 32, DDIM / 32, 2);
    prep_w<<<fgrid, 256, 0, stream>>>(Wcc, Wcp, Wt);

    // 2) GEMM + bias, both matrices in one launch (blockIdx.z)
    dim3 ggrid(NROWS / 64, DDIM / 128, 2);
    gemm_bias<<<ggrid, 256, 0, stream>>>(atoms, amino, Wt, bcc, bcp, out);
}

// Round 3
// 138.388 us; speedup vs baseline: 1.4643x; 1.2439x over previous
//
#include <hip/hip_runtime.h>
#include <hip/hip_bf16.h>

#define DDIM 512
#define NROWS 6144
#define BM 64
#define BN 128
#define BK 32
#define KSTEPS (DDIM / BK)  // 16

typedef __attribute__((ext_vector_type(8))) short short8;
typedef __attribute__((ext_vector_type(4))) float f32x4;

#define GLDS16(g, s)                                          \
  __builtin_amdgcn_global_load_lds(                           \
      (const __attribute__((address_space(1))) void*)(g),     \
      (__attribute__((address_space(3))) void*)(s), 16, 0, 0)

// ---------------------------------------------------------------------------
// Fold the 4 [512,512] k-blocks of W [2048,512] (sum), transpose to Wt[n][k],
// cast bf16.  32x32 LDS tiles, grid (16,16,2) = 512 blocks.
// ---------------------------------------------------------------------------
__global__ __launch_bounds__(256) void prep_w(
    const float* __restrict__ Wcc, const float* __restrict__ Wcp,
    __hip_bfloat16* __restrict__ Wt) {
    const float* W = blockIdx.z ? Wcp : Wcc;
    unsigned short* o = (unsigned short*)Wt + (size_t)blockIdx.z * DDIM * DDIM;
    __shared__ float lds[32][33];
    const int k0 = blockIdx.x * 32, n0 = blockIdx.y * 32;
    #pragma unroll
    for (int e = 0; e < 4; ++e) {
        int idx = e * 256 + threadIdx.x;
        int kk = idx >> 5, nn = idx & 31;
        float s = 0.f;
        #pragma unroll
        for (int i = 0; i < 4; ++i)
            s += W[(size_t)(i * DDIM + k0 + kk) * DDIM + n0 + nn];
        lds[kk][nn] = s;
    }
    __syncthreads();
    #pragma unroll
    for (int e = 0; e < 4; ++e) {
        int idx = e * 256 + threadIdx.x;
        int nn = idx >> 5, kk = idx & 31;
        __hip_bfloat16 h = __float2bfloat16(lds[kk][nn]);
        o[(size_t)(n0 + nn) * DDIM + k0 + kk] = *(unsigned short*)&h;
    }
}

// ---------------------------------------------------------------------------
// C[6144,512] = A_f32 @ W + bias.  m97 structure: global_load_lds width-16
// staging of A (f32, XOR-swizzled) and B (bf16 Wt[n][k], XOR-swizzled) into
// double-buffered LDS; 2-barrier K-loop; f32->bf16 cvt at fragment read.
// Tile 64x128, BK=32, 4 waves (wave tile 32x64 = 2x4 MFMA tiles).
// Grid (96,4,2) = 768 blocks = 3/CU.
// Swizzle (rule #21: linear glds dest + pre-swizzled source + swizzled read):
//   A row = 128 B = 8 slots of 16 B, slot ^= (row & 7)      -> 2-way (free)
//   B row =  64 B = 4 slots of 16 B, slot ^= ((row>>1) & 3) -> 2-way (free)
// ---------------------------------------------------------------------------
__global__ __launch_bounds__(256, 3) void gemm_bias(
    const float* __restrict__ Aat, const float* __restrict__ Aam,
    const __hip_bfloat16* __restrict__ Wtall,
    const float* __restrict__ bias0, const float* __restrict__ bias1,
    float* __restrict__ C) {
  __shared__ float As[2][BM * BK];           // 2 x 8 KB
  __shared__ unsigned short Bs[2][BN * BK];  // 2 x 8 KB

  const int z = blockIdx.z;
  const float* A = z ? Aam : Aat;
  const unsigned short* Wt = (const unsigned short*)Wtall + (size_t)z * DDIM * DDIM;
  const float* bias = z ? bias1 : bias0;
  float* Cz = C + (size_t)z * NROWS * DDIM;

  const int tid = threadIdx.x;
  const int w = tid >> 6, l = tid & 63;
  const int m0 = blockIdx.x * BM;
  const int n0 = blockIdx.y * BN;

  // staging sources (pre-swizzled) + wave-uniform LDS offsets
  const float* srcA0;
  const float* srcA1;
  const unsigned short* srcB0;
  const unsigned short* srcB1;
  {
    int r0 = w * 16 + (l >> 3);           // A instr 0: rows w*16 .. +7
    int r1 = r0 + 8;                      // A instr 1
    srcA0 = A + (size_t)(m0 + r0) * DDIM + (((l & 7) ^ (r0 & 7)) << 2);
    srcA1 = A + (size_t)(m0 + r1) * DDIM + (((l & 7) ^ (r1 & 7)) << 2);
    int q0 = w * 32 + (l >> 2);           // B instr 0: rows w*32 .. +15
    int q1 = q0 + 16;                     // B instr 1
    srcB0 = Wt + (size_t)(n0 + q0) * DDIM + (((l & 3) ^ ((q0 >> 1) & 3)) << 3);
    srcB1 = Wt + (size_t)(n0 + q1) * DDIM + (((l & 3) ^ ((q1 >> 1) & 3)) << 3);
  }
  const unsigned ldsA0 = (w * 2 + 0) * 256, ldsA1 = (w * 2 + 1) * 256;
  const unsigned ldsB0 = (w * 2 + 0) * 512, ldsB1 = (w * 2 + 1) * 512;

#define STAGE(buf, kk)                                 \
  do {                                                 \
    GLDS16(srcA0 + (kk) * BK, &As[buf][ldsA0]);        \
    GLDS16(srcA1 + (kk) * BK, &As[buf][ldsA1]);        \
    GLDS16(srcB0 + (kk) * BK, &Bs[buf][ldsB0]);        \
    GLDS16(srcB1 + (kk) * BK, &Bs[buf][ldsB1]);        \
  } while (0)

  f32x4 acc[2][4];
  #pragma unroll
  for (int i = 0; i < 2; ++i)
    #pragma unroll
    for (int j = 0; j < 4; ++j) acc[i][j] = (f32x4){0.f, 0.f, 0.f, 0.f};

  const int s0 = (l >> 4) * 2;   // A 16B-slot pair base (k-group)
  const int bs = (l >> 4);       // B 16B slot (k-group)
  const int lr = l & 15;

#define COMPUTE(buf)                                                          \
  do {                                                                        \
    short8 afr[2];                                                            \
    _Pragma("unroll")                                                         \
    for (int tm = 0; tm < 2; ++tm) {                                          \
      int r = (w >> 1) * 32 + tm * 16 + lr;                                   \
      f32x4 x0 = *(const f32x4*)&As[buf][r * BK + (((s0 + 0) ^ (r & 7)) << 2)]; \
      f32x4 x1 = *(const f32x4*)&As[buf][r * BK + (((s0 + 1) ^ (r & 7)) << 2)]; \
      float xv[8] = {x0[0], x0[1], x0[2], x0[3], x1[0], x1[1], x1[2], x1[3]}; \
      _Pragma("unroll")                                                       \
      for (int e = 0; e < 8; ++e) {                                           \
        __hip_bfloat16 h = __float2bfloat16(xv[e]);                           \
        afr[tm][e] = *(short*)&h;                                             \
      }                                                                       \
    }                                                                         \
    _Pragma("unroll")                                                         \
    for (int tn = 0; tn < 4; ++tn) {                                          \
      int r = (w & 1) * 64 + tn * 16 + lr;                                    \
      short8 bf = *(const short8*)&Bs[buf][r * BK + ((bs ^ ((r >> 1) & 3)) << 3)]; \
      acc[0][tn] = __builtin_amdgcn_mfma_f32_16x16x32_bf16(afr[0], bf, acc[0][tn], 0, 0, 0); \
      acc[1][tn] = __builtin_amdgcn_mfma_f32_16x16x32_bf16(afr[1], bf, acc[1][tn], 0, 0, 0); \
    }                                                                         \
  } while (0)

  // prologue
  STAGE(0, 0);
  __syncthreads();

  for (int t = 0; t < KSTEPS; t += 2) {
    STAGE(1, t + 1);          // t+1 <= 15 always
    COMPUTE(0);
    __syncthreads();
    if (t + 2 < KSTEPS) STAGE(0, t + 2);
    COMPUTE(1);
    __syncthreads();
  }

  // epilogue
  const int rg = (l >> 4) * 4;
  #pragma unroll
  for (int tn = 0; tn < 4; ++tn) {
    const int col = n0 + (w & 1) * 64 + tn * 16 + lr;
    const float bv = bias[col];
    #pragma unroll
    for (int tm = 0; tm < 2; ++tm) {
      const int row = m0 + (w >> 1) * 32 + tm * 16 + rg;
      #pragma unroll
      for (int r = 0; r < 4; ++r)
        Cz[(size_t)(row + r) * DDIM + col] = acc[tm][tn][r] + bv;
    }
  }
#undef STAGE
#undef COMPUTE
}

extern "C" void kernel_launch(void* const* d_in, const int* in_sizes, int n_in,
                              void* d_out, int out_size, void* d_ws, size_t ws_size,
                              hipStream_t stream) {
    const float* atoms = (const float*)d_in[0];   // [6144,512]
    const float* amino = (const float*)d_in[1];   // [6144,512]
    const float* Wcc   = (const float*)d_in[15];  // [2048,512]
    const float* bcc   = (const float*)d_in[16];  // [512]
    const float* Wcp   = (const float*)d_in[17];  // [2048,512]
    const float* bcp   = (const float*)d_in[18];  // [512]
    float* out = (float*)d_out;

    __hip_bfloat16* Wt = (__hip_bfloat16*)d_ws;   // [2][512][512] bf16 = 1 MB

    dim3 fgrid(DDIM / 32, DDIM / 32, 2);
    prep_w<<<fgrid, 256, 0, stream>>>(Wcc, Wcp, Wt);

    dim3 ggrid(NROWS / BM, DDIM / BN, 2);
    gemm_bias<<<ggrid, 256, 0, stream>>>(atoms, amino, Wt, bcc, bcp, out);
}

// Round 4
// 134.467 us; speedup vs baseline: 1.5070x; 1.0292x over previous
//
#include <hip/hip_runtime.h>
#include <hip/hip_bf16.h>

#define DDIM 512
#define NROWS 6144
#define BM 64
#define BN 128
#define BK 32
#define KSTEPS (DDIM / BK)  // 16

typedef __attribute__((ext_vector_type(8))) short short8;
typedef __attribute__((ext_vector_type(4))) float f32x4;

#define GLDS16(g, s)                                          \
  __builtin_amdgcn_global_load_lds(                           \
      (const __attribute__((address_space(1))) void*)(g),     \
      (__attribute__((address_space(3))) void*)(s), 16, 0, 0)

// ---------------------------------------------------------------------------
// Fold the 4 [512,512] k-blocks of W [2048,512] (sum), transpose to Wt[n][k],
// cast bf16.  Vectorized: float4 global reads, ushort4 (4x bf16) writes.
// Tile = 32 k-rows x 64 n-cols; grid (16, 8, 2) = 256 blocks.
// LDS [32][65] f32: scalar stores, stride-65 rows -> conflict-free transpose.
// ---------------------------------------------------------------------------
__global__ __launch_bounds__(256) void prep_w(
    const float* __restrict__ Wcc, const float* __restrict__ Wcp,
    __hip_bfloat16* __restrict__ Wt) {
    const float* W = blockIdx.z ? Wcp : Wcc;
    unsigned short* o = (unsigned short*)Wt + (size_t)blockIdx.z * DDIM * DDIM;
    __shared__ float lds[32][65];
    const int k0 = blockIdx.x * 32, n0 = blockIdx.y * 64;
    #pragma unroll
    for (int u = 0; u < 2; ++u) {
        int idx = u * 256 + threadIdx.x;
        int kk = idx >> 4, c = idx & 15;
        float4 s = {0.f, 0.f, 0.f, 0.f};
        #pragma unroll
        for (int i = 0; i < 4; ++i) {
            float4 v = *(const float4*)&W[(size_t)(i * DDIM + k0 + kk) * DDIM + n0 + c * 4];
            s.x += v.x; s.y += v.y; s.z += v.z; s.w += v.w;
        }
        lds[kk][c * 4 + 0] = s.x;
        lds[kk][c * 4 + 1] = s.y;
        lds[kk][c * 4 + 2] = s.z;
        lds[kk][c * 4 + 3] = s.w;
    }
    __syncthreads();
    #pragma unroll
    for (int u = 0; u < 2; ++u) {
        int idx = u * 256 + threadIdx.x;
        int nr = idx >> 3, kc = idx & 7;
        ushort4 p;
        #pragma unroll
        for (int j = 0; j < 4; ++j) {
            __hip_bfloat16 h = __float2bfloat16(lds[kc * 4 + j][nr]);
            ((unsigned short*)&p)[j] = *(unsigned short*)&h;
        }
        *(ushort4*)&o[(size_t)(n0 + nr) * DDIM + k0 + kc * 4] = p;
    }
}

// ---------------------------------------------------------------------------
// C[6144,512] = A_f32 @ W + bias.  T3/T4-lite: 3-buffer LDS, prefetch depth
// 2, ONE raw s_barrier per K-step, counted `s_waitcnt vmcnt(4)` (4 glds per
// stage; stages t,t+1 in flight -> vmcnt(4) waits exactly stage t).  Race
// safety: STAGE(t+2) writes buffer (t-1)%3, freed because every wave passed
// COMPUTE(t-1) before the iter-t barrier; vmcnt-before-barrier makes all
// waves' stage-t loads LDS-visible.  f32->bf16 cvt of A at fragment read.
// Tile 64x128, 4 waves (wave tile 32x64).  Grid (96,4,2) = 768 = 3/CU.
// Swizzle (rule #21): linear glds dest + pre-swizzled source + swizzled read.
//   A row = 128 B = 8 slots, slot ^= (row & 7)        -> 2-way (free)
//   B row =  64 B = 4 slots, slot ^= ((row>>1) & 3)   -> 2-way (free)
// ---------------------------------------------------------------------------
__global__ __launch_bounds__(256, 3) void gemm_bias(
    const float* __restrict__ Aat, const float* __restrict__ Aam,
    const __hip_bfloat16* __restrict__ Wtall,
    const float* __restrict__ bias0, const float* __restrict__ bias1,
    float* __restrict__ C) {
  __shared__ float As[3][BM * BK];           // 3 x 8 KB
  __shared__ unsigned short Bs[3][BN * BK];  // 3 x 8 KB

  const int z = blockIdx.z;
  const float* A = z ? Aam : Aat;
  const unsigned short* Wt = (const unsigned short*)Wtall + (size_t)z * DDIM * DDIM;
  const float* bias = z ? bias1 : bias0;
  float* Cz = C + (size_t)z * NROWS * DDIM;

  const int tid = threadIdx.x;
  const int w = tid >> 6, l = tid & 63;
  const int m0 = blockIdx.x * BM;
  const int n0 = blockIdx.y * BN;

  // staging sources (pre-swizzled) + wave-uniform LDS offsets
  const float* srcA0;
  const float* srcA1;
  const unsigned short* srcB0;
  const unsigned short* srcB1;
  {
    int r0 = w * 16 + (l >> 3);           // A instr 0: rows w*16 .. +7
    int r1 = r0 + 8;                      // A instr 1
    srcA0 = A + (size_t)(m0 + r0) * DDIM + (((l & 7) ^ (r0 & 7)) << 2);
    srcA1 = A + (size_t)(m0 + r1) * DDIM + (((l & 7) ^ (r1 & 7)) << 2);
    int q0 = w * 32 + (l >> 2);           // B instr 0: rows w*32 .. +15
    int q1 = q0 + 16;                     // B instr 1
    srcB0 = Wt + (size_t)(n0 + q0) * DDIM + (((l & 3) ^ ((q0 >> 1) & 3)) << 3);
    srcB1 = Wt + (size_t)(n0 + q1) * DDIM + (((l & 3) ^ ((q1 >> 1) & 3)) << 3);
  }
  const unsigned ldsA0 = (w * 2 + 0) * 256, ldsA1 = (w * 2 + 1) * 256;
  const unsigned ldsB0 = (w * 2 + 0) * 512, ldsB1 = (w * 2 + 1) * 512;

#define STAGE(buf, kk)                                 \
  do {                                                 \
    GLDS16(srcA0 + (kk) * BK, &As[buf][ldsA0]);        \
    GLDS16(srcA1 + (kk) * BK, &As[buf][ldsA1]);        \
    GLDS16(srcB0 + (kk) * BK, &Bs[buf][ldsB0]);        \
    GLDS16(srcB1 + (kk) * BK, &Bs[buf][ldsB1]);        \
  } while (0)

  f32x4 acc[2][4];
  #pragma unroll
  for (int i = 0; i < 2; ++i)
    #pragma unroll
    for (int j = 0; j < 4; ++j) acc[i][j] = (f32x4){0.f, 0.f, 0.f, 0.f};

  const int s0 = (l >> 4) * 2;   // A 16B-slot pair base (k-group)
  const int bs = (l >> 4);       // B 16B slot (k-group)
  const int lr = l & 15;

#define COMPUTE(buf)                                                          \
  do {                                                                        \
    short8 afr[2];                                                            \
    _Pragma("unroll")                                                         \
    for (int tm = 0; tm < 2; ++tm) {                                          \
      int r = (w >> 1) * 32 + tm * 16 + lr;                                   \
      f32x4 x0 = *(const f32x4*)&As[buf][r * BK + (((s0 + 0) ^ (r & 7)) << 2)]; \
      f32x4 x1 = *(const f32x4*)&As[buf][r * BK + (((s0 + 1) ^ (r & 7)) << 2)]; \
      float xv[8] = {x0[0], x0[1], x0[2], x0[3], x1[0], x1[1], x1[2], x1[3]}; \
      _Pragma("unroll")                                                       \
      for (int e = 0; e < 8; ++e) {                                           \
        __hip_bfloat16 h = __float2bfloat16(xv[e]);                           \
        afr[tm][e] = *(short*)&h;                                             \
      }                                                                       \
    }                                                                         \
    _Pragma("unroll")                                                         \
    for (int tn = 0; tn < 4; ++tn) {                                          \
      int r = (w & 1) * 64 + tn * 16 + lr;                                    \
      short8 bf = *(const short8*)&Bs[buf][r * BK + ((bs ^ ((r >> 1) & 3)) << 3)]; \
      acc[0][tn] = __builtin_amdgcn_mfma_f32_16x16x32_bf16(afr[0], bf, acc[0][tn], 0, 0, 0); \
      acc[1][tn] = __builtin_amdgcn_mfma_f32_16x16x32_bf16(afr[1], bf, acc[1][tn], 0, 0, 0); \
    }                                                                         \
  } while (0)

  // prologue: two stages in flight
  STAGE(0, 0);
  STAGE(1, 1);

  #pragma unroll
  for (int t = 0; t < KSTEPS; ++t) {
    if (t < KSTEPS - 1)
      asm volatile("s_waitcnt vmcnt(4)" ::: "memory");   // stage t done
    else
      asm volatile("s_waitcnt vmcnt(0)" ::: "memory");   // last stage
    __builtin_amdgcn_s_barrier();
    if (t + 2 < KSTEPS) STAGE((t + 2) % 3, t + 2);
    COMPUTE(t % 3);
  }

  // epilogue
  const int rg = (l >> 4) * 4;
  #pragma unroll
  for (int tn = 0; tn < 4; ++tn) {
    const int col = n0 + (w & 1) * 64 + tn * 16 + lr;
    const float bv = bias[col];
    #pragma unroll
    for (int tm = 0; tm < 2; ++tm) {
      const int row = m0 + (w >> 1) * 32 + tm * 16 + rg;
      #pragma unroll
      for (int r = 0; r < 4; ++r)
        Cz[(size_t)(row + r) * DDIM + col] = acc[tm][tn][r] + bv;
    }
  }
#undef STAGE
#undef COMPUTE
}

extern "C" void kernel_launch(void* const* d_in, const int* in_sizes, int n_in,
                              void* d_out, int out_size, void* d_ws, size_t ws_size,
                              hipStream_t stream) {
    const float* atoms = (const float*)d_in[0];   // [6144,512]
    const float* amino = (const float*)d_in[1];   // [6144,512]
    const float* Wcc   = (const float*)d_in[15];  // [2048,512]
    const float* bcc   = (const float*)d_in[16];  // [512]
    const float* Wcp   = (const float*)d_in[17];  // [2048,512]
    const float* bcp   = (const float*)d_in[18];  // [512]
    float* out = (float*)d_out;

    __hip_bfloat16* Wt = (__hip_bfloat16*)d_ws;   // [2][512][512] bf16 = 1 MB

    dim3 fgrid(DDIM / 32, DDIM / 64, 2);
    prep_w<<<fgrid, 256, 0, stream>>>(Wcc, Wcp, Wt);

    dim3 ggrid(NROWS / BM, DDIM / BN, 2);
    gemm_bias<<<ggrid, 256, 0, stream>>>(atoms, amino, Wt, bcc, bcp, out);
}